// Round 1
// baseline (429.958 us; speedup 1.0000x reference)
//
#include <hip/hip_runtime.h>

// YOLO-style loss: pred/target (N, 7, 7, 30) f32 -> 5 scalar losses.
// Memory-bound streaming reduction. 256 cells per block staged to LDS via
// coalesced float4 loads; one thread computes one cell; hierarchical
// reduction (wave shuffle -> LDS -> atomicAdd).

#define S_GRID 7
#define D_CH   30
#define CELLS_PER_BLOCK 256
#define TILE_FLOATS (CELLS_PER_BLOCK * D_CH)  // 7680
#define THREADS 256

__global__ __launch_bounds__(THREADS) void yolo_loss_kernel(
    const float* __restrict__ pred, const float* __restrict__ tgt,
    float* __restrict__ out, long long totalCells, float inv_n)
{
    __shared__ float sp[TILE_FLOATS];
    __shared__ float st[TILE_FLOATS];
    __shared__ float red[THREADS / 64][5];

    const int tid = threadIdx.x;
    const long long cell0 = (long long)blockIdx.x * CELLS_PER_BLOCK;
    const long long base = cell0 * D_CH;
    const long long totalFloats = totalCells * (long long)D_CH;
    long long remLL = totalFloats - base;
    const int numFloats = (remLL > (long long)TILE_FLOATS) ? TILE_FLOATS : (int)remLL;

    // ---- stage: coalesced float4 loads (base is 7680-float aligned -> 16B ok)
    const float4* gp4 = reinterpret_cast<const float4*>(pred + base);
    const float4* gt4 = reinterpret_cast<const float4*>(tgt + base);
    float4* sp4 = reinterpret_cast<float4*>(sp);
    float4* st4 = reinterpret_cast<float4*>(st);
    const int n4 = numFloats >> 2;
    for (int i = tid; i < n4; i += THREADS) sp4[i] = gp4[i];
    for (int i = tid; i < n4; i += THREADS) st4[i] = gt4[i];
    for (int i = (n4 << 2) + tid; i < numFloats; i += THREADS) {
        sp[i] = pred[base + i];
        st[i] = tgt[base + i];
    }
    __syncthreads();

    float lxy = 0.f, lwh = 0.f, lobj = 0.f, lnoobj = 0.f, lcls = 0.f;

    if (cell0 + tid < totalCells) {
        const float* P = sp + tid * D_CH;
        const float* T = st + tid * D_CH;
        const float cellw = 1.0f / (float)S_GRID;

        const float t4 = T[4];
        const float obj   = (t4 == 1.0f) ? 1.0f : 0.0f;
        const float noobj = (t4 == 0.0f) ? 1.0f : 0.0f;

        // target box 0 in ltrb
        const float tlx = T[0] * cellw - T[2] * 0.5f;
        const float tly = T[1] * cellw - T[3] * 0.5f;
        const float trx = T[0] * cellw + T[2] * 0.5f;
        const float tby = T[1] * cellw + T[3] * 0.5f;
        const float area_t = (trx - tlx) * (tby - tly);

        float iou0, iou1;
        #pragma unroll
        for (int b = 0; b < 2; ++b) {
            const float* Pb = P + b * 5;
            const float plx = Pb[0] * cellw - Pb[2] * 0.5f;
            const float ply = Pb[1] * cellw - Pb[3] * 0.5f;
            const float prx = Pb[0] * cellw + Pb[2] * 0.5f;
            const float pby = Pb[1] * cellw + Pb[3] * 0.5f;
            const float ltx = fmaxf(plx, tlx);
            const float lty = fmaxf(ply, tly);
            const float rbx = fminf(prx, trx);
            const float rby = fminf(pby, tby);
            const float wx = fmaxf(rbx - ltx, 0.0f);
            const float wy = fmaxf(rby - lty, 0.0f);
            const float inter = wx * wy;
            const float area_p = (prx - plx) * (pby - ply);
            const float v = inter / (area_p + area_t - inter);
            if (b == 0) iou0 = v; else iou1 = v;
        }

        // argmax first-occurrence tie-break: idx 1 only if strictly greater
        const int bi = (iou1 > iou0) ? 1 : 0;
        const float riou = fmaxf(iou0, iou1);

        const float* Pb = P + bi * 5;
        const float* Tb = T + bi * 5;
        const float dx = Tb[0] - Pb[0];
        const float dy = Tb[1] - Pb[1];
        lxy = obj * (dx * dx + dy * dy);

        const float dw = sqrtf(Tb[2]) - sqrtf(Pb[2]);
        const float dh = sqrtf(Tb[3]) - sqrtf(Pb[3]);
        lwh = obj * (dw * dw + dh * dh);

        const float dc = riou - Pb[4];
        lobj = obj * (dc * dc);

        const float d4 = T[4] - P[4];
        const float d9 = T[9] - P[9];
        lnoobj = noobj * (d4 * d4 + d9 * d9);

        float cs = 0.f;
        #pragma unroll
        for (int c = 10; c < 30; ++c) {
            const float d = T[c] - P[c];
            cs += d * d;
        }
        lcls = obj * cs;
    }

    // ---- reduction: wave(64) shuffle -> LDS across waves -> atomicAdd
    #pragma unroll
    for (int off = 32; off > 0; off >>= 1) {
        lxy    += __shfl_down(lxy, off);
        lwh    += __shfl_down(lwh, off);
        lobj   += __shfl_down(lobj, off);
        lnoobj += __shfl_down(lnoobj, off);
        lcls   += __shfl_down(lcls, off);
    }
    const int wave = tid >> 6;
    const int lane = tid & 63;
    if (lane == 0) {
        red[wave][0] = lxy;
        red[wave][1] = lwh;
        red[wave][2] = lobj;
        red[wave][3] = lnoobj;
        red[wave][4] = lcls;
    }
    __syncthreads();
    if (tid == 0) {
        float v0 = 0.f, v1 = 0.f, v2 = 0.f, v3 = 0.f, v4 = 0.f;
        #pragma unroll
        for (int w = 0; w < THREADS / 64; ++w) {
            v0 += red[w][0];
            v1 += red[w][1];
            v2 += red[w][2];
            v3 += red[w][3];
            v4 += red[w][4];
        }
        atomicAdd(&out[0], v0 * inv_n);
        atomicAdd(&out[1], v1 * inv_n);
        atomicAdd(&out[2], v2 * inv_n);
        atomicAdd(&out[3], v3 * inv_n);
        atomicAdd(&out[4], v4 * inv_n);
    }
}

extern "C" void kernel_launch(void* const* d_in, const int* in_sizes, int n_in,
                              void* d_out, int out_size, void* d_ws, size_t ws_size,
                              hipStream_t stream) {
    const float* pred = (const float*)d_in[0];
    const float* tgt  = (const float*)d_in[1];
    float* out = (float*)d_out;

    const long long totalFloats = (long long)in_sizes[0];
    const long long totalCells = totalFloats / D_CH;               // N*S*S
    const long long n = totalCells / (S_GRID * S_GRID);            // N
    const float inv_n = 1.0f / (float)n;

    hipMemsetAsync(out, 0, 5 * sizeof(float), stream);

    const int blocks = (int)((totalCells + CELLS_PER_BLOCK - 1) / CELLS_PER_BLOCK);
    yolo_loss_kernel<<<blocks, THREADS, 0, stream>>>(pred, tgt, out, totalCells, inv_n);
}

// Round 2
// 72.176 us; speedup vs baseline: 5.9571x; 5.9571x over previous
//
#include <hip/hip_runtime.h>

// YOLO-style loss: pred/target (N, 7, 7, 30) f32 -> 5 scalar losses.
// HBM-streaming reduction. Persistent blocks grid-stride over 256-cell tiles;
// each tile (pred+tgt, 61440 B) staged to LDS with 15 unrolled float4 loads
// per thread (deep in-flight pipeline); one thread computes one cell.
// NO global atomics: per-block partials -> d_ws, tiny second kernel reduces.

#define S_GRID 7
#define D_CH   30
#define CELLS_PER_TILE 256
#define TILE_F4 ((CELLS_PER_TILE * D_CH) / 4)   // 1920 float4 per tensor
#define BOTH_F4 (2 * TILE_F4)                   // 3840 float4 staged
#define THREADS 256
#define GRID_BLOCKS 1024

__global__ __launch_bounds__(THREADS) void yolo_loss_partial(
    const float* __restrict__ pred, const float* __restrict__ tgt,
    float* __restrict__ ws, int nTiles, long long totalCells)
{
    __shared__ float4 stage[BOTH_F4];             // pred tile then tgt tile
    __shared__ float red[THREADS / 64][5];

    const int tid = threadIdx.x;
    const float* sp = reinterpret_cast<const float*>(stage);
    const float* st = reinterpret_cast<const float*>(stage + TILE_F4);

    float lxy = 0.f, lwh = 0.f, lobj = 0.f, lnoobj = 0.f, lcls = 0.f;

    for (int tile = blockIdx.x; tile < nTiles; tile += gridDim.x) {
        const long long cell0 = (long long)tile * CELLS_PER_TILE;
        const float4* gp4 = reinterpret_cast<const float4*>(pred + cell0 * D_CH);
        const float4* gt4 = reinterpret_cast<const float4*>(tgt + cell0 * D_CH);

        __syncthreads();   // previous iteration's readers done before overwrite

        const bool full = (cell0 + CELLS_PER_TILE) <= totalCells;
        if (full) {
            // 15 independent float4 loads per thread, fully unrolled -> deep MLP
            #pragma unroll
            for (int j = 0; j < 15; ++j) {
                const int k = tid + j * THREADS;
                const float4* src = (k < TILE_F4) ? (gp4 + k) : (gt4 + (k - TILE_F4));
                stage[k] = *src;
            }
        } else {
            const long long totalFloats = totalCells * (long long)D_CH;
            const long long baseF = cell0 * (long long)D_CH;
            float* s = reinterpret_cast<float*>(stage);
            for (int f = tid; f < CELLS_PER_TILE * D_CH; f += THREADS) {
                const bool ok = (baseF + f) < totalFloats;
                s[f]                      = ok ? pred[baseF + f] : 0.f;
                s[TILE_F4 * 4 + f]        = ok ? tgt[baseF + f]  : 0.f;
            }
        }
        __syncthreads();

        if (cell0 + tid < totalCells) {
            const float* P = sp + tid * D_CH;
            const float* T = st + tid * D_CH;
            const float cellw = 1.0f / (float)S_GRID;

            const float t4 = T[4];
            const float obj   = (t4 == 1.0f) ? 1.0f : 0.0f;
            const float noobj = (t4 == 0.0f) ? 1.0f : 0.0f;

            // target box 0 in ltrb
            const float tlx = T[0] * cellw - T[2] * 0.5f;
            const float tly = T[1] * cellw - T[3] * 0.5f;
            const float trx = T[0] * cellw + T[2] * 0.5f;
            const float tby = T[1] * cellw + T[3] * 0.5f;
            const float area_t = (trx - tlx) * (tby - tly);

            float iou0 = 0.f, iou1 = 0.f;
            #pragma unroll
            for (int b = 0; b < 2; ++b) {
                const float* Pb = P + b * 5;
                const float plx = Pb[0] * cellw - Pb[2] * 0.5f;
                const float ply = Pb[1] * cellw - Pb[3] * 0.5f;
                const float prx = Pb[0] * cellw + Pb[2] * 0.5f;
                const float pby = Pb[1] * cellw + Pb[3] * 0.5f;
                const float ltx = fmaxf(plx, tlx);
                const float lty = fmaxf(ply, tly);
                const float rbx = fminf(prx, trx);
                const float rby = fminf(pby, tby);
                const float wx = fmaxf(rbx - ltx, 0.0f);
                const float wy = fmaxf(rby - lty, 0.0f);
                const float inter = wx * wy;
                const float area_p = (prx - plx) * (pby - ply);
                const float v = inter / (area_p + area_t - inter);
                if (b == 0) iou0 = v; else iou1 = v;
            }

            // argmax first-occurrence tie-break: idx 1 only if strictly greater
            const int bi = (iou1 > iou0) ? 1 : 0;
            const float riou = fmaxf(iou0, iou1);

            const float* Pb = P + bi * 5;
            const float* Tb = T + bi * 5;
            const float dx = Tb[0] - Pb[0];
            const float dy = Tb[1] - Pb[1];
            lxy += obj * (dx * dx + dy * dy);

            const float dw = sqrtf(Tb[2]) - sqrtf(Pb[2]);
            const float dh = sqrtf(Tb[3]) - sqrtf(Pb[3]);
            lwh += obj * (dw * dw + dh * dh);

            const float dc = riou - Pb[4];
            lobj += obj * (dc * dc);

            const float d4 = T[4] - P[4];
            const float d9 = T[9] - P[9];
            lnoobj += noobj * (d4 * d4 + d9 * d9);

            float cs = 0.f;
            #pragma unroll
            for (int c = 10; c < 30; ++c) {
                const float d = T[c] - P[c];
                cs += d * d;
            }
            lcls += obj * cs;
        }
    }

    // ---- block reduction: wave(64) shuffle -> LDS across waves -> ws store
    #pragma unroll
    for (int off = 32; off > 0; off >>= 1) {
        lxy    += __shfl_down(lxy, off);
        lwh    += __shfl_down(lwh, off);
        lobj   += __shfl_down(lobj, off);
        lnoobj += __shfl_down(lnoobj, off);
        lcls   += __shfl_down(lcls, off);
    }
    const int wave = tid >> 6;
    const int lane = tid & 63;
    if (lane == 0) {
        red[wave][0] = lxy;
        red[wave][1] = lwh;
        red[wave][2] = lobj;
        red[wave][3] = lnoobj;
        red[wave][4] = lcls;
    }
    __syncthreads();
    if (tid < 5) {
        float v = 0.f;
        #pragma unroll
        for (int w = 0; w < THREADS / 64; ++w) v += red[w][tid];
        ws[(long long)blockIdx.x * 5 + tid] = v;
    }
}

__global__ __launch_bounds__(256) void yolo_loss_reduce(
    const float* __restrict__ ws, float* __restrict__ out,
    int nParts, float inv_n)
{
    __shared__ float red[4][5];
    const int tid = threadIdx.x;
    float s0 = 0.f, s1 = 0.f, s2 = 0.f, s3 = 0.f, s4 = 0.f;
    for (int b = tid; b < nParts; b += 256) {
        const float* p = ws + (long long)b * 5;
        s0 += p[0]; s1 += p[1]; s2 += p[2]; s3 += p[3]; s4 += p[4];
    }
    #pragma unroll
    for (int off = 32; off > 0; off >>= 1) {
        s0 += __shfl_down(s0, off);
        s1 += __shfl_down(s1, off);
        s2 += __shfl_down(s2, off);
        s3 += __shfl_down(s3, off);
        s4 += __shfl_down(s4, off);
    }
    const int wave = tid >> 6;
    const int lane = tid & 63;
    if (lane == 0) {
        red[wave][0] = s0; red[wave][1] = s1; red[wave][2] = s2;
        red[wave][3] = s3; red[wave][4] = s4;
    }
    __syncthreads();
    if (tid < 5) {
        float v = 0.f;
        #pragma unroll
        for (int w = 0; w < 4; ++w) v += red[w][tid];
        out[tid] = v * inv_n;
    }
}

extern "C" void kernel_launch(void* const* d_in, const int* in_sizes, int n_in,
                              void* d_out, int out_size, void* d_ws, size_t ws_size,
                              hipStream_t stream) {
    const float* pred = (const float*)d_in[0];
    const float* tgt  = (const float*)d_in[1];
    float* out = (float*)d_out;
    float* ws  = (float*)d_ws;

    const long long totalFloats = (long long)in_sizes[0];
    const long long totalCells = totalFloats / D_CH;                    // N*S*S
    const long long n = totalCells / (S_GRID * S_GRID);                 // N
    const float inv_n = 1.0f / (float)n;

    const int nTiles = (int)((totalCells + CELLS_PER_TILE - 1) / CELLS_PER_TILE);
    const int blocks = (nTiles < GRID_BLOCKS) ? nTiles : GRID_BLOCKS;

    yolo_loss_partial<<<blocks, THREADS, 0, stream>>>(pred, tgt, ws, nTiles, totalCells);
    yolo_loss_reduce<<<1, 256, 0, stream>>>(ws, out, blocks, inv_n);
}